// Round 3
// baseline (856.617 us; speedup 1.0000x reference)
//
#include <hip/hip_runtime.h>
#include <math.h>

// clDice topology loss, round 3: dword-domain packed-fp16 morphology.
// Region 96x96 per 64x64 tile (halo 16). LDS rows of 52 dwords (48 data +
// 4 pad preset to +BIG), plus guard rows -1 and 96 preset to +BIG.
// Erode: branchless rowmin via shared v_alignbit chain (5 ab + 8 pk_min/row),
// 6-row register-rotated sweeps, 12 chunks x 16 segs = 192 threads.
// Dilate: interior-only, 2 rows x 8 halfs per thread, -BIG edge substitution.
// One barrier per iteration. 2 x 20384B LDS -> 4 blocks/CU.

typedef unsigned int u32;
typedef _Float16 h2 __attribute__((ext_vector_type(2)));

#define STRD 52
#define BB   0x7BFF7BFFu   // +65504,+65504  (erode pad)
#define NB   0xFBFFFBFFu   // -65504,-65504  (dilate edge substitute)

__device__ __forceinline__ u32 ab(u32 hi, u32 lo) {
#if __has_builtin(__builtin_amdgcn_alignbit)
  return __builtin_amdgcn_alignbit(hi, lo, 16);
#else
  return (u32)(((((unsigned long long)hi) << 32) | lo) >> 16);
#endif
}
__device__ __forceinline__ u32 bcu(h2 x) { return __builtin_bit_cast(u32, x); }
__device__ __forceinline__ h2  bch(u32 x) { return __builtin_bit_cast(h2, x); }
__device__ __forceinline__ u32 pmin(u32 a, u32 b) {
  return bcu(__builtin_elementwise_min(bch(a), bch(b)));
}
__device__ __forceinline__ u32 pmax(u32 a, u32 b) {
  return bcu(__builtin_elementwise_max(bch(a), bch(b)));
}
__device__ __forceinline__ u32 pmin3(u32 a, u32 b, u32 c) { return pmin(pmin(a, b), c); }
__device__ __forceinline__ u32 pmax3(u32 a, u32 b, u32 c) { return pmax(pmax(a, b), c); }

__device__ __forceinline__ uint4 v4min3(uint4 a, uint4 b, uint4 c) {
  return make_uint4(pmin3(a.x, b.x, c.x), pmin3(a.y, b.y, c.y),
                    pmin3(a.z, b.z, c.z), pmin3(a.w, b.w, c.w));
}
__device__ __forceinline__ uint4 v4max3(uint4 a, uint4 b, uint4 c) {
  return make_uint4(pmax3(a.x, b.x, c.x), pmax3(a.y, b.y, c.y),
                    pmax3(a.z, b.z, c.z), pmax3(a.w, b.w, c.w));
}

// 3-wide horizontal min of one 8-half row chunk (halos from LDS, branch-free)
__device__ __forceinline__ uint4 rowmin8(const u32* __restrict__ p) {
  uint4 v = *(const uint4*)p;
  u32 hl = p[-1], hr = p[4];
  u32 m0 = ab(v.x, hl), m1 = ab(v.y, v.x), m2 = ab(v.z, v.y),
      m3 = ab(v.w, v.z), m4 = ab(hr, v.w);
  return make_uint4(pmin3(m0, v.x, m1), pmin3(m1, v.y, m2),
                    pmin3(m2, v.z, m3), pmin3(m3, v.w, m4));
}

// 3-wide horizontal max with image-edge substitution; v preloaded by caller
__device__ __forceinline__ uint4 rowmax8v(const u32* __restrict__ p, uint4 v,
                                          bool lc, bool rc) {
  u32 hl = p[-1]; hl = lc ? NB : hl;
  u32 hr = p[4];  hr = rc ? NB : hr;
  u32 m0 = ab(v.x, hl), m1 = ab(v.y, v.x), m2 = ab(v.z, v.y),
      m3 = ab(v.w, v.z), m4 = ab(hr, v.w);
  return make_uint4(pmax3(m0, v.x, m1), pmax3(m1, v.y, m2),
                    pmax3(m2, v.z, m3), pmax3(m3, v.w, m4));
}

__device__ __forceinline__ u32 skup(u32 sk, u32 im, u32 op) {
  h2 d = bch(im) - bch(op);
  h2 z = {(_Float16)0, (_Float16)0};
  d = __builtin_elementwise_max(d, z);
  return bcu(__builtin_elementwise_max(bch(sk), d));
}

__device__ __forceinline__ float sigmoidf_(float x) {
  return 1.0f / (1.0f + __expf(-x));
}

__global__ __launch_bounds__(256, 4) void skel_tile_kernel(
    const float* __restrict__ pred, const float* __restrict__ gt,
    float* __restrict__ sums)
{
  __shared__ __align__(16) u32 LA[STRD * 98];
  __shared__ __align__(16) u32 LB[STRD * 98];
  u32* const Ad = LA + STRD;  // data row 0
  u32* const Bd = LB + STRD;

  const int tile = blockIdx.x;   // 16x16 tiles of 64x64
  const int b    = blockIdx.y;   // batch 0..31
  const int s    = blockIdx.z;   // 0: skel(sigmoid(pred)), 1: skel(gt)
  const int txI = tile & 15, tyI = tile >> 4;
  const int x0 = txI * 64 - 16, y0 = tyI * 64 - 16;
  const int t  = threadIdx.x;
  const size_t base = (size_t)b << 20;
  const float* __restrict__ src  = s ? gt   : pred;
  const float* __restrict__ osrc = s ? pred : gt;

  // ---- init guard rows (-1, 96) and pad dwords 48..51 of rows 0..95 ----
  for (int i = t; i < 104; i += 256) {
    int idx = (i < 52) ? i : STRD * 97 + (i - 52);
    LA[idx] = BB; LB[idx] = BB;
  }
  for (int i = t; i < 384; i += 256) {
    int r = i >> 2, c = 48 + (i & 3);
    Ad[r * STRD + c] = BB; Bd[r * STRD + c] = BB;
  }

  // ---- load 96 rows x 12 chunks of 8 halfs; out-of-image = +BIG ----
  for (int i = t; i < 96 * 12; i += 256) {
    int ci = i % 12, row = i / 12;
    int gy = y0 + row, gx0 = x0 + ci * 8;
    uint4 hv;
    if ((unsigned)gy < 1024u && gx0 >= 0 && gx0 + 8 <= 1024) {
      const size_t g = base + (size_t)gy * 1024 + gx0;
      const float4 f0 = *(const float4*)&src[g];
      const float4 f1 = *(const float4*)&src[g + 4];
      float ff[8] = {f0.x, f0.y, f0.z, f0.w, f1.x, f1.y, f1.z, f1.w};
      u32 d[4];
      #pragma unroll
      for (int e = 0; e < 4; ++e) {
        float a = ff[2 * e], bb2 = ff[2 * e + 1];
        if (s == 0) { a = sigmoidf_(a); bb2 = sigmoidf_(bb2); }
        h2 p; p[0] = (_Float16)a; p[1] = (_Float16)bb2;
        d[e] = bcu(p);
      }
      hv = make_uint4(d[0], d[1], d[2], d[3]);
    } else {
      u32 d[4];
      #pragma unroll
      for (int e = 0; e < 4; ++e) {
        float va = 65504.0f, vb = 65504.0f;
        int gxa = gx0 + 2 * e, gxb = gxa + 1;
        if ((unsigned)gy < 1024u && (unsigned)gxa < 1024u) {
          va = src[base + (size_t)gy * 1024 + gxa];
          if (s == 0) va = sigmoidf_(va);
        }
        if ((unsigned)gy < 1024u && (unsigned)gxb < 1024u) {
          vb = src[base + (size_t)gy * 1024 + gxb];
          if (s == 0) vb = sigmoidf_(vb);
        }
        h2 p; p[0] = (_Float16)va; p[1] = (_Float16)vb;
        d[e] = bcu(p);
      }
      hv = make_uint4(d[0], d[1], d[2], d[3]);
    }
    *(uint4*)&Ad[row * STRD + ci * 4] = hv;
  }
  __syncthreads();

  // ---- ownerships ----
  // dilate/skel: interior 64x64 -> chunks 2..9, 2-row segs
  const int cid = 2 + (t & 7), rsd = 16 + (t >> 3) * 2;
  const int gxd = x0 + cid * 8;
  const bool lc = (gxd == 0), rc = (gxd + 8 == 1024);
  const bool bu0 = (y0 + rsd) >= 1;          // only select needed for row jj=0
  const bool bd1 = (y0 + rsd + 1) <= 1022;   // only select needed for row jj=1
  const int dOff = (rsd - 1) * STRD + cid * 4;

  uint4 img0 = *(const uint4*)&Ad[rsd * STRD + cid * 4];
  uint4 img1 = *(const uint4*)&Ad[(rsd + 1) * STRD + cid * 4];
  uint4 sk0 = make_uint4(0, 0, 0, 0), sk1 = make_uint4(0, 0, 0, 0);

  // erode: 12 chunks x 16 six-row segs = 192 threads
  const int ci_e = t % 12, rse = (t / 12) * 6;
  const int eOffR = (rse - 1) * STRD + ci_e * 4;   // may be -52+.. -> guard row
  const int eOffW = rse * STRD + ci_e * 4;

  u32 *P = Ad, *Q = Bd;
  const uint4 NB4 = make_uint4(NB, NB, NB, NB);

  for (int k = 0; k < 10; ++k) {
    // ---- erode P -> Q (branch-free, register-rotated) ----
    if (t < 192) {
      const u32* __restrict__ pr = P + eOffR;
      u32* __restrict__ qw = Q + eOffW;
      uint4 r0 = rowmin8(pr);
      uint4 r1 = rowmin8(pr + STRD);
      #pragma unroll
      for (int j = 0; j < 6; ++j) {
        uint4 r2 = rowmin8(pr + (j + 2) * STRD);
        *(uint4*)(qw + j * STRD) = v4min3(r0, r1, r2);
        r0 = r1; r1 = r2;
      }
    }
    __syncthreads();

    // ---- dilate(Q) at interior -> registers; skel update ----
    {
      const u32* __restrict__ qr = Q + dOff;
      uint4 v0 = *(const uint4*)qr;
      uint4 v1 = *(const uint4*)(qr + STRD);
      uint4 v2 = *(const uint4*)(qr + 2 * STRD);
      uint4 v3 = *(const uint4*)(qr + 3 * STRD);
      uint4 r0 = rowmax8v(qr, v0, lc, rc);
      uint4 r1 = rowmax8v(qr + STRD, v1, lc, rc);
      uint4 r2 = rowmax8v(qr + 2 * STRD, v2, lc, rc);
      uint4 r3 = rowmax8v(qr + 3 * STRD, v3, lc, rc);
      uint4 up0 = bu0 ? r0 : NB4;
      uint4 dn1 = bd1 ? r3 : NB4;
      uint4 op0 = v4max3(up0, r1, r2);
      uint4 op1 = v4max3(r1, r2, dn1);
      sk0.x = skup(sk0.x, img0.x, op0.x); sk0.y = skup(sk0.y, img0.y, op0.y);
      sk0.z = skup(sk0.z, img0.z, op0.z); sk0.w = skup(sk0.w, img0.w, op0.w);
      sk1.x = skup(sk1.x, img1.x, op1.x); sk1.y = skup(sk1.y, img1.y, op1.y);
      sk1.z = skup(sk1.z, img1.z, op1.z); sk1.w = skup(sk1.w, img1.w, op1.w);
      img0 = v1; img1 = v2;
    }
    { u32* tmp = P; P = Q; Q = tmp; }
  }

  // ---- fused reduction: s0 = sum(skel*other), s1 = sum(skel) ----
  float s0 = 0.f, s1 = 0.f;
  {
    const u32 skr[2][4] = {{sk0.x, sk0.y, sk0.z, sk0.w},
                           {sk1.x, sk1.y, sk1.z, sk1.w}};
    #pragma unroll
    for (int jj = 0; jj < 2; ++jj) {
      const int gy = y0 + rsd + jj;
      const size_t g = base + (size_t)gy * 1024 + gxd;
      const float4 f0 = *(const float4*)&osrc[g];
      const float4 f1 = *(const float4*)&osrc[g + 4];
      float ff[8] = {f0.x, f0.y, f0.z, f0.w, f1.x, f1.y, f1.z, f1.w};
      #pragma unroll
      for (int e = 0; e < 4; ++e) {
        h2 q = bch(skr[jj][e]);
        float o0 = ff[2 * e], o1 = ff[2 * e + 1];
        if (s == 1) { o0 = sigmoidf_(o0); o1 = sigmoidf_(o1); }
        float q0 = (float)q[0], q1 = (float)q[1];
        s0 += q0 * o0 + q1 * o1;
        s1 += q0 + q1;
      }
    }
  }
  for (int off = 32; off >= 1; off >>= 1) {
    s0 += __shfl_down(s0, off, 64);
    s1 += __shfl_down(s1, off, 64);
  }
  __syncthreads();  // last dilate reads done before reusing LA
  float* red = (float*)LA;
  const int lane = t & 63, wv = t >> 6;
  if (lane == 0) { red[wv * 2] = s0; red[wv * 2 + 1] = s1; }
  __syncthreads();
  if (t == 0) {
    atomicAdd(&sums[(s * 32 + b) * 2 + 0], red[0] + red[2] + red[4] + red[6]);
    atomicAdd(&sums[(s * 32 + b) * 2 + 1], red[1] + red[3] + red[5] + red[7]);
  }
}

__global__ void finalize_kernel(const float* __restrict__ sums,
                                float* __restrict__ out)
{
  const int t = threadIdx.x;  // 64 threads
  float cl = 0.f;
  if (t < 32) {
    float pn = sums[t * 2 + 0],        pd = sums[t * 2 + 1];
    float sn = sums[(32 + t) * 2 + 0], sd = sums[(32 + t) * 2 + 1];
    float tprec = pn / (pd + 1e-6f);
    float tsens = sn / (sd + 1e-6f);
    cl = 2.f * tprec * tsens / (tprec + tsens + 1e-6f);
  }
  for (int off = 32; off >= 1; off >>= 1) cl += __shfl_down(cl, off, 64);
  if (t == 0) out[0] = 1.f - cl / 32.f;
}

extern "C" void kernel_launch(void* const* d_in, const int* in_sizes, int n_in,
                              void* d_out, int out_size, void* d_ws, size_t ws_size,
                              hipStream_t stream) {
  const float* pred = (const float*)d_in[0];
  const float* gt   = (const float*)d_in[1];
  float* sums = (float*)d_ws;  // 128 floats: [tensor][batch][{prod,sum}]
  hipMemsetAsync(sums, 0, 128 * sizeof(float), stream);
  dim3 grid(256, 32, 2);
  skel_tile_kernel<<<grid, dim3(256), 0, stream>>>(pred, gt, sums);
  finalize_kernel<<<1, 64, 0, stream>>>(sums, (float*)d_out);
}

// Round 4
// 802.077 us; speedup vs baseline: 1.0680x; 1.0680x over previous
//
#include <hip/hip_runtime.h>
#include <math.h>

// clDice topology loss, round 4: all-b128 LDS + bpermute halos + pipelined
// erode||dilate. Region 96x96 halfs (48 dw) per 64x64 tile, stride 52 dw,
// guard rows -1/96 = +BIG. Waves 0-1: erode (12-dw chunks x4, 3-row segs).
// Waves 2-3: dilate of previous iter (1 row/lane, half-row 24-dw read span).
// 11 phases, 1 barrier each. 2 x 20384B LDS -> 4 blocks/CU.

typedef unsigned int u32;
typedef _Float16 h2 __attribute__((ext_vector_type(2)));

#define STRD 52
#define BB   0x7BFF7BFFu   // +65504 x2 (erode pad)
#define NB   0xFBFFFBFFu   // -65504 x2 (dilate edge substitute)

__device__ __forceinline__ u32 ab(u32 hi, u32 lo) {
  return __builtin_amdgcn_alignbit(hi, lo, 16);
}
__device__ __forceinline__ u32 bcu(h2 x) { return __builtin_bit_cast(u32, x); }
__device__ __forceinline__ h2  bch(u32 x) { return __builtin_bit_cast(h2, x); }
__device__ __forceinline__ u32 pmin(u32 a, u32 b) {
  return bcu(__builtin_elementwise_min(bch(a), bch(b)));
}
__device__ __forceinline__ u32 pmax(u32 a, u32 b) {
  return bcu(__builtin_elementwise_max(bch(a), bch(b)));
}
__device__ __forceinline__ u32 pmin3(u32 a, u32 b, u32 c) { return pmin(pmin(a, b), c); }
__device__ __forceinline__ u32 pmax3(u32 a, u32 b, u32 c) { return pmax(pmax(a, b), c); }
__device__ __forceinline__ u32 skup(u32 sk, u32 im, u32 op) {
  h2 d = bch(im) - bch(op);
  h2 z = {(_Float16)0, (_Float16)0};
  d = __builtin_elementwise_max(d, z);
  return bcu(__builtin_elementwise_max(bch(sk), d));
}
__device__ __forceinline__ float sigmoidf_(float x) {
  return 1.0f / (1.0f + __expf(-x));
}

// 3-wide horizontal min over a 12-dw chunk; halos via ds_bpermute.
__device__ __forceinline__ void rowmin12(const u32* __restrict__ p,
                                         int pu, int pd, bool c0, bool c3,
                                         u32* __restrict__ out) {
  uint4 a = *(const uint4*)p;
  uint4 b = *(const uint4*)(p + 4);
  uint4 c = *(const uint4*)(p + 8);
  u32 v0=a.x, v1=a.y, v2=a.z, v3=a.w, v4=b.x, v5=b.y, v6=b.z, v7=b.w,
      v8=c.x, v9=c.y, v10=c.z, v11=c.w;
  u32 hl = (u32)__builtin_amdgcn_ds_bpermute(pu, (int)v11);
  u32 hr = (u32)__builtin_amdgcn_ds_bpermute(pd, (int)v0);
  hl = c0 ? BB : hl;
  hr = c3 ? BB : hr;
  u32 m0 = ab(v0, hl), m1 = ab(v1, v0), m2 = ab(v2, v1), m3 = ab(v3, v2),
      m4 = ab(v4, v3), m5 = ab(v5, v4), m6 = ab(v6, v5), m7 = ab(v7, v6),
      m8 = ab(v8, v7), m9 = ab(v9, v8), m10 = ab(v10, v9), m11 = ab(v11, v10),
      m12 = ab(hr, v11);
  out[0] = pmin3(m0, v0, m1);   out[1] = pmin3(m1, v1, m2);
  out[2] = pmin3(m2, v2, m3);   out[3] = pmin3(m3, v3, m4);
  out[4] = pmin3(m4, v4, m5);   out[5] = pmin3(m5, v5, m6);
  out[6] = pmin3(m6, v6, m7);   out[7] = pmin3(m7, v7, m8);
  out[8] = pmin3(m8, v8, m9);   out[9] = pmin3(m9, v9, m10);
  out[10] = pmin3(m10, v10, m11); out[11] = pmin3(m11, v11, m12);
}

__device__ __forceinline__ void emin3_store(u32* __restrict__ w,
    const u32* __restrict__ a, const u32* __restrict__ b,
    const u32* __restrict__ c) {
  #pragma unroll
  for (int g = 0; g < 3; ++g) {
    uint4 o;
    o.x = pmin3(a[4*g],   b[4*g],   c[4*g]);
    o.y = pmin3(a[4*g+1], b[4*g+1], c[4*g+1]);
    o.z = pmin3(a[4*g+2], b[4*g+2], c[4*g+2]);
    o.w = pmin3(a[4*g+3], b[4*g+3], c[4*g+3]);
    *(uint4*)(w + 4*g) = o;
  }
}

// Read 24 dwords (6xb128), apply image-edge fixes, 3-wide horizontal max
// producing eh[16] for out dwords idx 4..19. RAW: also export raw center data.
template <bool RAW>
__device__ __forceinline__ void load_eh(const u32* __restrict__ p,
                                        bool lfix, bool rfix,
                                        u32* __restrict__ eh,
                                        u32* __restrict__ raw16) {
  u32 dw[24];
  #pragma unroll
  for (int i = 0; i < 6; ++i) {
    uint4 v = *(const uint4*)(p + 4 * i);
    dw[4*i] = v.x; dw[4*i+1] = v.y; dw[4*i+2] = v.z; dw[4*i+3] = v.w;
  }
  if (RAW) {
    #pragma unroll
    for (int i = 0; i < 16; ++i) raw16[i] = dw[i + 4];
  }
  if (lfix) dw[3]  = (dw[3]  & 0x0000FFFFu) | 0xFBFF0000u;  // half 15 -> -BIG
  if (rfix) dw[20] = (dw[20] & 0xFFFF0000u) | 0x0000FBFFu;  // half 80 -> -BIG
  u32 m0 = ab(dw[4], dw[3]);
  #pragma unroll
  for (int i = 0; i < 16; ++i) {
    u32 m1 = ab(dw[i + 5], dw[i + 4]);
    eh[i] = pmax3(m0, dw[i + 4], m1);
    m0 = m1;
  }
}

__global__ __launch_bounds__(256, 4) void skel_tile_kernel(
    const float* __restrict__ pred, const float* __restrict__ gt,
    float* __restrict__ sums)
{
  __shared__ __align__(16) u32 LA[STRD * 98];
  __shared__ __align__(16) u32 LB[STRD * 98];
  u32* const Ad = LA + STRD;  // data row 0
  u32* const Bd = LB + STRD;

  const int tile = blockIdx.x;   // 16x16 tiles of 64x64
  const int b    = blockIdx.y;   // batch 0..31
  const int s    = blockIdx.z;   // 0: skel(sigmoid(pred)), 1: skel(gt)
  const int txI = tile & 15, tyI = tile >> 4;
  const int x0 = txI * 64 - 16, y0 = tyI * 64 - 16;
  const int t  = threadIdx.x;
  const size_t base = (size_t)b << 20;
  const float* __restrict__ src  = s ? gt   : pred;
  const float* __restrict__ osrc = s ? pred : gt;

  // ---- guard rows -1 and 96 = +BIG in both buffers ----
  for (int i = t; i < 104; i += 256) {
    int idx = (i < 52) ? i : STRD * 97 + (i - 52);
    LA[idx] = BB; LB[idx] = BB;
  }

  // ---- load 96 rows x 12 chunks of 8 halfs; out-of-image = +BIG ----
  for (int i = t; i < 96 * 12; i += 256) {
    int ci = i % 12, row = i / 12;
    int gy = y0 + row, gx0 = x0 + ci * 8;
    uint4 hv;
    if ((unsigned)gy < 1024u && gx0 >= 0 && gx0 + 8 <= 1024) {
      const size_t g = base + (size_t)gy * 1024 + gx0;
      const float4 f0 = *(const float4*)&src[g];
      const float4 f1 = *(const float4*)&src[g + 4];
      float ff[8] = {f0.x, f0.y, f0.z, f0.w, f1.x, f1.y, f1.z, f1.w};
      u32 d[4];
      #pragma unroll
      for (int e = 0; e < 4; ++e) {
        float a = ff[2 * e], bb2 = ff[2 * e + 1];
        if (s == 0) { a = sigmoidf_(a); bb2 = sigmoidf_(bb2); }
        h2 p; p[0] = (_Float16)a; p[1] = (_Float16)bb2;
        d[e] = bcu(p);
      }
      hv = make_uint4(d[0], d[1], d[2], d[3]);
    } else {
      u32 d[4];
      #pragma unroll
      for (int e = 0; e < 4; ++e) {
        float va = 65504.0f, vb = 65504.0f;
        int gxa = gx0 + 2 * e, gxb = gxa + 1;
        if ((unsigned)gy < 1024u && (unsigned)gxa < 1024u) {
          va = src[base + (size_t)gy * 1024 + gxa];
          if (s == 0) va = sigmoidf_(va);
        }
        if ((unsigned)gy < 1024u && (unsigned)gxb < 1024u) {
          vb = src[base + (size_t)gy * 1024 + gxb];
          if (s == 0) vb = sigmoidf_(vb);
        }
        h2 p; p[0] = (_Float16)va; p[1] = (_Float16)vb;
        d[e] = bcu(p);
      }
      hv = make_uint4(d[0], d[1], d[2], d[3]);
    }
    *(uint4*)&Ad[row * STRD + ci * 4] = hv;
  }
  __syncthreads();

  const int lane = t & 63, wid = t >> 6;

  // erode role (waves 0-1): seg = t>>2 (0..31), chunk ec = t&3
  const int seg = t >> 2, ec = t & 3;
  const int ea = 3 * seg;
  const bool c0 = (ec == 0), c3 = (ec == 3);
  const int pu = ((lane - 1) & 63) * 4;
  const int pd = ((lane + 1) & 63) * 4;
  const int eoff = 12 * ec;

  // dilate role (waves 2-3): q = wid-2, row dr = 16+lane
  const int q  = wid - 2;
  const int dr = 16 + lane;
  const int db = 4 + 16 * q;          // first dword of 24-dw read span
  const int gyD = y0 + dr;
  const bool bu = (gyD >= 1), bd = (gyD <= 1022);
  const bool lfix = (q == 0) && (txI == 0);
  const bool rfix = (q == 1) && (txI == 15);

  u32 skel[16], img[16];
  #pragma unroll
  for (int i = 0; i < 16; ++i) skel[i] = 0;

  u32 *P = Ad, *Q = Bd;

  for (int ph = 0; ph <= 10; ++ph) {
    if (wid < 2) {
      if (ph < 10) {
        const u32* pr = P + (ea - 1) * STRD + eoff;
        u32* qw = Q + ea * STRD + eoff;
        u32 r0[12], r1[12], r2[12];
        rowmin12(pr,            pu, pd, c0, c3, r0);
        rowmin12(pr + STRD,     pu, pd, c0, c3, r1);
        rowmin12(pr + 2 * STRD, pu, pd, c0, c3, r2);
        emin3_store(qw, r0, r1, r2);
        rowmin12(pr + 3 * STRD, pu, pd, c0, c3, r0);
        emin3_store(qw + STRD, r1, r2, r0);
        rowmin12(pr + 4 * STRD, pu, pd, c0, c3, r1);
        emin3_store(qw + 2 * STRD, r2, r0, r1);
      }
    } else {
      if (ph == 0) {
        // img_0 = raw P_0 at out idx 4..19 of center row
        const u32* p = P + dr * STRD + db;
        #pragma unroll
        for (int i = 0; i < 4; ++i) {
          uint4 v = *(const uint4*)(p + 4 + 4 * i);
          img[4*i] = v.x; img[4*i+1] = v.y; img[4*i+2] = v.z; img[4*i+3] = v.w;
        }
      } else {
        // dilate iter ph-1: opened = colmax(rowmax(E)), E = P (erode's source)
        const u32* pD = P + (dr - 1) * STRD + db;
        u32 eh[16], op[16], imgn[16];
        load_eh<false>(pD, lfix, rfix, eh, nullptr);
        #pragma unroll
        for (int i = 0; i < 16; ++i) op[i] = bu ? eh[i] : NB;
        load_eh<true>(pD + STRD, lfix, rfix, eh, imgn);
        #pragma unroll
        for (int i = 0; i < 16; ++i) op[i] = pmax(op[i], eh[i]);
        load_eh<false>(pD + 2 * STRD, lfix, rfix, eh, nullptr);
        #pragma unroll
        for (int i = 0; i < 16; ++i) op[i] = pmax(op[i], bd ? eh[i] : NB);
        #pragma unroll
        for (int i = 0; i < 16; ++i) skel[i] = skup(skel[i], img[i], op[i]);
        #pragma unroll
        for (int i = 0; i < 16; ++i) img[i] = imgn[i];
      }
    }
    __syncthreads();
    u32* tmp = P; P = Q; Q = tmp;
  }

  // ---- fused reduction: s0 = sum(skel*other), s1 = sum(skel) ----
  float s0 = 0.f, s1 = 0.f;
  if (wid >= 2) {
    const int gxb = x0 + 2 * db + 8;  // global col of first skel half
    const size_t g = base + (size_t)gyD * 1024 + gxb;
    #pragma unroll
    for (int v4i = 0; v4i < 8; ++v4i) {
      const float4 f = *(const float4*)&osrc[g + 4 * v4i];
      float o0 = f.x, o1 = f.y, o2 = f.z, o3 = f.w;
      if (s == 1) {
        o0 = sigmoidf_(o0); o1 = sigmoidf_(o1);
        o2 = sigmoidf_(o2); o3 = sigmoidf_(o3);
      }
      h2 qa = bch(skel[2 * v4i]);
      h2 qb = bch(skel[2 * v4i + 1]);
      float a0 = (float)qa[0], a1 = (float)qa[1];
      float a2 = (float)qb[0], a3 = (float)qb[1];
      s0 += a0 * o0 + a1 * o1 + a2 * o2 + a3 * o3;
      s1 += a0 + a1 + a2 + a3;
    }
  }
  for (int off = 32; off >= 1; off >>= 1) {
    s0 += __shfl_down(s0, off, 64);
    s1 += __shfl_down(s1, off, 64);
  }
  float* red = (float*)LA;
  if (lane == 0) { red[wid * 2] = s0; red[wid * 2 + 1] = s1; }
  __syncthreads();
  if (t == 0) {
    atomicAdd(&sums[(s * 32 + b) * 2 + 0], red[4] + red[6]);
    atomicAdd(&sums[(s * 32 + b) * 2 + 1], red[5] + red[7]);
  }
}

__global__ void finalize_kernel(const float* __restrict__ sums,
                                float* __restrict__ out)
{
  const int t = threadIdx.x;  // 64 threads
  float cl = 0.f;
  if (t < 32) {
    float pn = sums[t * 2 + 0],        pd = sums[t * 2 + 1];
    float sn = sums[(32 + t) * 2 + 0], sd = sums[(32 + t) * 2 + 1];
    float tprec = pn / (pd + 1e-6f);
    float tsens = sn / (sd + 1e-6f);
    cl = 2.f * tprec * tsens / (tprec + tsens + 1e-6f);
  }
  for (int off = 32; off >= 1; off >>= 1) cl += __shfl_down(cl, off, 64);
  if (t == 0) out[0] = 1.f - cl / 32.f;
}

extern "C" void kernel_launch(void* const* d_in, const int* in_sizes, int n_in,
                              void* d_out, int out_size, void* d_ws, size_t ws_size,
                              hipStream_t stream) {
  const float* pred = (const float*)d_in[0];
  const float* gt   = (const float*)d_in[1];
  float* sums = (float*)d_ws;  // 128 floats: [tensor][batch][{prod,sum}]
  hipMemsetAsync(sums, 0, 128 * sizeof(float), stream);
  dim3 grid(256, 32, 2);
  skel_tile_kernel<<<grid, dim3(256), 0, stream>>>(pred, gt, sums);
  finalize_kernel<<<1, 64, 0, stream>>>(sums, (float*)d_out);
}